// Round 1
// baseline (5882.133 us; speedup 1.0000x reference)
//
#include <hip/hip_runtime.h>
#include <hip/hip_fp16.h>

// ---------------------------------------------------------------------------
// 4-layer GRU stack (Keras reset_after), B=128, T=384, U=D=256.
// Single persistent kernel: 32 blocks = 4 layers x 8 batch-chunks (16 rows).
// Layer pipeline via flags in ws; per-step GEMM = [x_t|h](16x512) @ W(512x768)
// with fp16 MFMA 16x16x32, fp32 accumulate. Weights pre-repacked into
// B-fragment order (coalesced dwordx4, L2-resident: 3 MB total).
// ---------------------------------------------------------------------------

#define LAYERS 4
#define BATCH  128
#define TSTEPS 384
#define UNITS  256
#define NG     768            // 3*UNITS (gate cols: z | r | h)
#define MCH    16             // batch rows per chunk
#define NCHUNK 8
#define AP     520            // A_lds row pitch in fp16 elems (512 + 8 pad)
#define WPL    (48 * 16 * 64 * 8)   // 393216 fp16 weight elems per layer
#define TILE_STRIDE (16 * 64 * 8)   // 8192 elems per col-tile

typedef _Float16 half8 __attribute__((ext_vector_type(8)));
typedef float    f32x4 __attribute__((ext_vector_type(4)));

// ws layout (bytes)
#define WP_OFF   0
#define BP_OFF   (LAYERS * WPL * 2)          // 3,145,728
#define FLAG_OFF (BP_OFF + LAYERS * 1024 * 4)
#define FLAG_BYTES 4096
#define LINK_OFF (4 * 1024 * 1024)
#define LINK_ELEMS ((size_t)BATCH * TSTEPS * UNITS)   // fp16 elems per link
#define FLAG_STRIDE 16   // dwords (64 B per flag)

// ---------------------------------------------------------------------------
// Repack: W[l] -> [tile=48][kt=16][lane=64][8] fp16 fragments, where
// n = tile*16 + (lane&15), k = kt*32 + (lane>>4)*8 + j.  k<256 = input kernel,
// k>=256 = recurrent kernel. Bias: [0:512]=b_in+b_rec (z,r), [512:768]=b_in_h,
// [768:1024]=b_rec_h.
// ---------------------------------------------------------------------------
__global__ void repack_kernel(const float* __restrict__ k0, const float* __restrict__ rk0,
                              const float* __restrict__ b0, const float* __restrict__ kern,
                              const float* __restrict__ rkern, const float* __restrict__ bias,
                              _Float16* __restrict__ Wp, float* __restrict__ Bp)
{
    int idx = blockIdx.x * 256 + threadIdx.x;
    const int total_w = LAYERS * WPL;
    if (idx < total_w) {
        int l = idx / WPL;
        int r = idx - l * WPL;
        int j    = r & 7;
        int lane = (r >> 3) & 63;
        int kt   = (r >> 9) & 15;
        int tile = r >> 13;
        int n = tile * 16 + (lane & 15);
        int k = kt * 32 + (lane >> 4) * 8 + j;
        float v;
        if (l == 0) {
            v = (k < 256) ? k0[(size_t)k * NG + n] : rk0[(size_t)(k - 256) * NG + n];
        } else {
            const float* kk = kern  + (size_t)(l - 1) * 256 * NG;
            const float* rk = rkern + (size_t)(l - 1) * 256 * NG;
            v = (k < 256) ? kk[(size_t)k * NG + n] : rk[(size_t)(k - 256) * NG + n];
        }
        Wp[idx] = (_Float16)v;
    } else {
        int ib = idx - total_w;
        if (ib < LAYERS * 1024) {
            int l = ib >> 10;
            int i = ib & 1023;
            const float* bs = (l == 0) ? b0 : (bias + (size_t)(l - 1) * 2 * NG);
            float v;
            if (i < 512)      v = bs[i] + bs[NG + i];          // z,r: b_in + b_rec
            else if (i < 768) v = bs[512 + (i - 512)];          // b_in for h gate
            else              v = bs[NG + 512 + (i - 768)];     // b_rec for h gate
            Bp[l * 1024 + i] = v;
        }
    }
}

// ---------------------------------------------------------------------------
// Persistent pipelined GRU kernel. 512 threads = 8 waves; wave w owns units
// [32w, 32w+32): col-tiles {2w,2w+1} in each of z/r/h blocks (6 MFMA tiles).
// ---------------------------------------------------------------------------
__launch_bounds__(512, 1)
__global__ void gru_kernel(const float* __restrict__ x,
                           const _Float16* __restrict__ Wp,
                           const float* __restrict__ Bp,
                           _Float16* __restrict__ links,
                           unsigned int* __restrict__ flags,
                           float* __restrict__ out)
{
    __shared__ _Float16 Alds[MCH * AP];

    const int tid   = threadIdx.x;
    const int lane  = tid & 63;
    const int w     = tid >> 6;
    const int chunk = blockIdx.x & 7;     // round-robin -> one chunk per XCD,
    const int l     = blockIdx.x >> 3;    // all 4 layers of a chunk on same XCD
    const int b0row = chunk * MCH;

    const int m16 = tid >> 5;   // staging: row 0..15
    const int l32 = tid & 31;   // staging: 8-elem group within row

    const _Float16* wbase = Wp + (size_t)l * WPL;
    const float*    bp    = Bp + l * 1024;

    _Float16*       link_out = links + (size_t)l * LINK_ELEMS;             // valid l<3
    const _Float16* link_in  = links + (size_t)(l > 0 ? l - 1 : 0) * LINK_ELEMS;

    unsigned int* flag_out = flags + ((l < 3 ? l : 0) * NCHUNK + chunk) * FLAG_STRIDE;
    unsigned int* flag_in  = flags + (((l > 0 ? l : 1) - 1) * NCHUNK + chunk) * FLAG_STRIDE;

    const int lo16 = lane & 15;
    const int q    = lane >> 4;

    // B-fragment stream pointers (one per owned col-tile)
    const half8* pz0 = (const half8*)(wbase + (size_t)(2 * w)      * TILE_STRIDE + lane * 8);
    const half8* pz1 = (const half8*)(wbase + (size_t)(2 * w + 1)  * TILE_STRIDE + lane * 8);
    const half8* pr0 = (const half8*)(wbase + (size_t)(16 + 2 * w) * TILE_STRIDE + lane * 8);
    const half8* pr1 = (const half8*)(wbase + (size_t)(17 + 2 * w) * TILE_STRIDE + lane * 8);
    const half8* ph0 = (const half8*)(wbase + (size_t)(32 + 2 * w) * TILE_STRIDE + lane * 8);
    const half8* ph1 = (const half8*)(wbase + (size_t)(33 + 2 * w) * TILE_STRIDE + lane * 8);

    const int u0 = w * 32 + lo16;
    const int u1 = u0 + 16;
    const float bz0v = bp[u0],       bz1v = bp[u1];
    const float br0v = bp[256 + u0], br1v = bp[256 + u1];
    const float bi0v = bp[512 + u0], bi1v = bp[512 + u1];
    const float bh0v = bp[768 + u0], bh1v = bp[768 + u1];

    float hreg[2][4] = {{0.f,0.f,0.f,0.f},{0.f,0.f,0.f,0.f}};

    auto wait_in = [&](int tneed) {
        if (l > 0) {
            while ((int)__hip_atomic_load(flag_in, __ATOMIC_RELAXED,
                                          __HIP_MEMORY_SCOPE_AGENT) < tneed) { }
        }
    };
    auto load_input = [&](int t) {
        if (l == 0) {
            const float* s = x + ((size_t)(b0row + m16) * TSTEPS + t) * UNITS + l32 * 8;
            f32x4 v0 = *(const f32x4*)s;
            f32x4 v1 = *(const f32x4*)(s + 4);
            half8 hv;
            hv[0] = (_Float16)v0[0]; hv[1] = (_Float16)v0[1];
            hv[2] = (_Float16)v0[2]; hv[3] = (_Float16)v0[3];
            hv[4] = (_Float16)v1[0]; hv[5] = (_Float16)v1[1];
            hv[6] = (_Float16)v1[2]; hv[7] = (_Float16)v1[3];
            *(half8*)(Alds + m16 * AP + l32 * 8) = hv;
        } else {
            // relaxed agent-scope loads: sc1 (bypass local L2), no acquire fence
            const unsigned long long* s = (const unsigned long long*)
                (link_in + ((size_t)(b0row + m16) * TSTEPS + t) * UNITS) + l32 * 2;
            unsigned long long q0 = __hip_atomic_load(s,     __ATOMIC_RELAXED, __HIP_MEMORY_SCOPE_AGENT);
            unsigned long long q1 = __hip_atomic_load(s + 1, __ATOMIC_RELAXED, __HIP_MEMORY_SCOPE_AGENT);
            *(unsigned long long*)(Alds + m16 * AP + l32 * 8)     = q0;
            *(unsigned long long*)(Alds + m16 * AP + l32 * 8 + 4) = q1;
        }
    };

    // prologue: zero h-half of A, load x_0
    *(unsigned long long*)(Alds + m16 * AP + 256 + l32 * 8)     = 0ull;
    *(unsigned long long*)(Alds + m16 * AP + 256 + l32 * 8 + 4) = 0ull;
    wait_in(1);
    load_input(0);
    __syncthreads();

    const half8* ap = (const half8*)(Alds + lo16 * AP + q * 8);

    for (int t = 0; t < TSTEPS; ++t) {
        f32x4 az0 = {0,0,0,0}, az1 = {0,0,0,0}, ar0 = {0,0,0,0}, ar1 = {0,0,0,0};
        f32x4 ai0 = {0,0,0,0}, ai1 = {0,0,0,0}, ah0 = {0,0,0,0}, ah1 = {0,0,0,0};
#pragma unroll
        for (int kt = 0; kt < 16; ++kt) {
            half8 a = ap[kt * 4];
            az0 = __builtin_amdgcn_mfma_f32_16x16x32_f16(a, pz0[kt * 64], az0, 0, 0, 0);
            az1 = __builtin_amdgcn_mfma_f32_16x16x32_f16(a, pz1[kt * 64], az1, 0, 0, 0);
            ar0 = __builtin_amdgcn_mfma_f32_16x16x32_f16(a, pr0[kt * 64], ar0, 0, 0, 0);
            ar1 = __builtin_amdgcn_mfma_f32_16x16x32_f16(a, pr1[kt * 64], ar1, 0, 0, 0);
            if (kt < 8) {   // k<256: input-kernel part of h-gate (mh)
                ai0 = __builtin_amdgcn_mfma_f32_16x16x32_f16(a, ph0[kt * 64], ai0, 0, 0, 0);
                ai1 = __builtin_amdgcn_mfma_f32_16x16x32_f16(a, ph1[kt * 64], ai1, 0, 0, 0);
            } else {        // k>=256: recurrent part of h-gate (rhh)
                ah0 = __builtin_amdgcn_mfma_f32_16x16x32_f16(a, ph0[kt * 64], ah0, 0, 0, 0);
                ah1 = __builtin_amdgcn_mfma_f32_16x16x32_f16(a, ph1[kt * 64], ah1, 0, 0, 0);
            }
        }
        // gates (fp32): z=sig(mz+rz), r=sig(mr+rr), hh=tanh(mh + r*rhh)
#pragma unroll
        for (int i = 0; i < 2; ++i) {
            f32x4 az = i ? az1 : az0, ar = i ? ar1 : ar0;
            f32x4 ai = i ? ai1 : ai0, ah = i ? ah1 : ah0;
            float bz = i ? bz1v : bz0v, br = i ? br1v : br0v;
            float bi = i ? bi1v : bi0v, bh = i ? bh1v : bh0v;
#pragma unroll
            for (int r = 0; r < 4; ++r) {
                float z  = 1.f / (1.f + __expf(-(az[r] + bz)));
                float rr = 1.f / (1.f + __expf(-(ar[r] + br)));
                float pre = (ai[r] + bi) + rr * (ah[r] + bh);
                float e  = __expf(2.f * pre);
                float th = 1.f - 2.f / (e + 1.f);   // tanh, saturates correctly
                hreg[i][r] = z * hreg[i][r] + (1.f - z) * th;
            }
        }
        __syncthreads();   // barrier 1: all waves done reading A_lds(t)

        // write h_t into A h-half (fp16) + link buffer (plain stores)
#pragma unroll
        for (int i = 0; i < 2; ++i) {
#pragma unroll
            for (int r = 0; r < 4; ++r) {
                int mm = q * 4 + r;
                int uu = w * 32 + i * 16 + lo16;
                _Float16 hf = (_Float16)hreg[i][r];
                Alds[mm * AP + 256 + uu] = hf;
                if (l < 3)
                    link_out[((size_t)(b0row + mm) * TSTEPS + t) * UNITS + uu] = hf;
            }
        }
        if (t + 1 < TSTEPS) {
            wait_in(t + 2);        // producer has written step t+1
            load_input(t + 1);
        } else if (l == 3) {
#pragma unroll
            for (int i = 0; i < 2; ++i) {
#pragma unroll
                for (int r = 0; r < 4; ++r) {
                    int mm = q * 4 + r;
                    int uu = w * 32 + i * 16 + lo16;
                    out[(size_t)(b0row + mm) * UNITS + uu] = hreg[i][r];
                }
            }
        }
        __syncthreads();   // barrier 2: drains all waves' stores (vmcnt 0)

        if (l < 3 && tid == 0) {
            // release-only agent fence: buffer_wbl2 (dirty lines only -> weight
            // lines stay cached). No acquire/inv anywhere in the hot loop.
            __builtin_amdgcn_fence(__ATOMIC_RELEASE, "agent");
            __hip_atomic_store(flag_out, (unsigned)(t + 1),
                               __ATOMIC_RELAXED, __HIP_MEMORY_SCOPE_AGENT);
        }
    }
}

extern "C" void kernel_launch(void* const* d_in, const int* in_sizes, int n_in,
                              void* d_out, int out_size, void* d_ws, size_t ws_size,
                              hipStream_t stream)
{
    const float* x     = (const float*)d_in[0];
    const float* k0    = (const float*)d_in[1];
    const float* rk0   = (const float*)d_in[2];
    const float* b0    = (const float*)d_in[3];
    const float* kern  = (const float*)d_in[4];
    const float* rkern = (const float*)d_in[5];
    const float* bias  = (const float*)d_in[6];
    float* out = (float*)d_out;

    char* ws = (char*)d_ws;
    _Float16*     Wp    = (_Float16*)(ws + WP_OFF);
    float*        Bp    = (float*)(ws + BP_OFF);
    unsigned int* flags = (unsigned int*)(ws + FLAG_OFF);
    _Float16*     links = (_Float16*)(ws + LINK_OFF);

    hipMemsetAsync(flags, 0, FLAG_BYTES, stream);

    const int total = LAYERS * WPL + LAYERS * 1024;
    repack_kernel<<<(total + 255) / 256, 256, 0, stream>>>(k0, rk0, b0, kern, rkern, bias, Wp, Bp);

    gru_kernel<<<LAYERS * NCHUNK, 512, 0, stream>>>(x, Wp, Bp, links, flags, out);
}